// Round 5
// baseline (274.283 us; speedup 1.0000x reference)
//
#include <hip/hip_runtime.h>
#include <math.h>

// Problem constants (fixed by the reference setup)
#define B_ 4
#define N_ 6400
#define D_ 32
#define TJ 256          // j-chunk staged in LDS (k_pass)
#define TI 128          // anchors per k_pass block (4 waves x 2 i-tiles x 16)
#define CHUNK 256       // compaction chunk
#define NCC 25          // N_/CHUNK
#define NCLS 20         // gt classes in [0,20)
#define CSROW 24        // padded row stride for per-batch classStart[21]
// packed triangular k_pass grid: NI = N_/TI = 50, NJ = N_/TJ = 25.
// keep (bi,bj) iff bi*TI < (bj+1)*TJ  <=>  bi <= 2*bj+1  -> nbi(bj) = 2*bj+2
// cum(bj) = bj*(bj+1); total = 24*25 + 50 = 650
#define NPASS 650

typedef __attribute__((ext_vector_type(4))) float f32x4;
typedef __attribute__((ext_vector_type(8))) short bf16x8;

static constexpr float MARGIN_ = 0.3f;

// monotone float<->uint map so atomicMax(uint) == float max
__device__ __forceinline__ unsigned fmap(float f) {
    unsigned u = __float_as_uint(f);
    return (u & 0x80000000u) ? ~u : (u | 0x80000000u);
}
__device__ __forceinline__ float funmap(unsigned u) {
    return (u & 0x80000000u) ? __uint_as_float(u ^ 0x80000000u)
                             : __uint_as_float(~u);
}
#define NEG_INF_MAPPED 0x007FFFFFu   // fmap(-inf)

// round-to-nearest-even f32 -> bf16
__device__ __forceinline__ unsigned short f2bf(float f) {
    unsigned u = __float_as_uint(f);
    unsigned r = u + 0x7fffu + ((u >> 16) & 1u);
    return (unsigned short)(r >> 16);
}
__device__ __forceinline__ float bf2f(unsigned short h) {
    return __uint_as_float(((unsigned)h) << 16);
}
// unpack packed bf16 pair (elem even in low 16, odd in high 16)
__device__ __forceinline__ void bf2x(unsigned u, float& e0, float& e1) {
    e0 = __uint_as_float(u << 16);
    e1 = __uint_as_float(u & 0xffff0000u);
}
// fp32-reconstructed dot of one packed pair (hi+lo splits)
__device__ __forceinline__ float dpair(unsigned xh, unsigned xl, unsigned yh, unsigned yl) {
    float a0, a1, b0, b1, c0, c1, d0, d1;
    bf2x(xh, a0, a1); bf2x(xl, b0, b1);
    bf2x(yh, c0, c1); bf2x(yl, d0, d1);
    return fmaf(a0 + b0, c0 + d0, (a1 + b1) * (c1 + d1));
}

// ---------------- Kernel 1: prep = stable counting-sort by class ----------------
// grid (25, B) x 256. Each block counts ALL (chunk,class) pairs of its batch via
// LDS atomics (waves split chunks), derives classStart[] + per-chunk/per-wave
// offsets, then scatters its own chunk's fg elements CLASS-SORTED (stable by
// original index): writes normalized hi/lo bf16 rows, clist (orig idx), cgS
// (class). Block c==0 also writes Marr[b] and csArr[b][0..20]. Inits bestArr
// and all tickets/counters (re-poison-safe: prep completes before pass starts).
__global__ __launch_bounds__(256) void k_prep(const float* __restrict__ pred,
                                              const int* __restrict__ gt,
                                              const int* __restrict__ fg,
                                              unsigned short* __restrict__ hi_g,
                                              unsigned short* __restrict__ lo_g,
                                              int* __restrict__ clist,
                                              int* __restrict__ cgS,
                                              int* __restrict__ Marr,
                                              int* __restrict__ csArr,
                                              unsigned* __restrict__ bestArr,
                                              unsigned* __restrict__ passDone,
                                              unsigned* __restrict__ combDone) {
    int c = blockIdx.x, b = blockIdx.y;
    int t = threadIdx.x, lane = t & 63, w = t >> 6;
    int idx = c * CHUNK + t;

    bestArr[b * N_ + idx] = NEG_INF_MAPPED;
    if (c == 0 && t == 0) passDone[b] = 0u;
    if (c == 0 && b == 0 && t == 0) *combDone = 0u;

    __shared__ int cntL[NCC * NCLS];   // per-(chunk,class) counts, whole batch
    __shared__ int wv[4 * NCLS];       // own-chunk per-wave class counts
    __shared__ int totL[NCLS];
    __shared__ int csL[NCLS + 1];
    for (int k = t; k < NCC * NCLS; k += 256) cntL[k] = 0;
    __syncthreads();

    // phase 1: count all chunks; wave w takes chunks w, w+4, ...
    for (int cc = w; cc < NCC; cc += 4) {
        const int4 f4 = ((const int4*)(fg + (size_t)b * N_ + cc * CHUNK))[lane];
        const int4 g4 = ((const int4*)(gt + (size_t)b * N_ + cc * CHUNK))[lane];
        if (f4.x) atomicAdd(&cntL[cc * NCLS + g4.x], 1);
        if (f4.y) atomicAdd(&cntL[cc * NCLS + g4.y], 1);
        if (f4.z) atomicAdd(&cntL[cc * NCLS + g4.z], 1);
        if (f4.w) atomicAdd(&cntL[cc * NCLS + g4.w], 1);
    }

    // own element: stable rank within (own chunk, class)
    bool flag = fg[b * N_ + idx] != 0;
    int cls = flag ? gt[b * N_ + idx] : 0;
    int rnk = 0;
    unsigned long long below = (1ull << lane) - 1ull;
    for (int k = 0; k < NCLS; ++k) {
        unsigned long long m = __ballot(flag && (cls == k));
        if (flag && cls == k) rnk = __popcll(m & below);
        if (lane == 0) wv[w * NCLS + k] = __popcll(m);
    }
    __syncthreads();

    // phase 2: class totals and exclusive prefix (classStart)
    if (t < NCLS) {
        int s = 0;
        #pragma unroll
        for (int cc = 0; cc < NCC; ++cc) s += cntL[cc * NCLS + t];
        totL[t] = s;
    }
    __syncthreads();
    if (t <= NCLS) {
        int s = 0;
        for (int k = 0; k < t; ++k) s += totL[k];
        csL[t] = s;
    }
    __syncthreads();
    if (c == 0) {
        if (t == 0) Marr[b] = csL[NCLS];
        if (t <= NCLS) csArr[b * CSROW + t] = csL[t];
    }
    if (!flag) return;   // no further barriers below

    // phase 3: destination = classStart + chunks-before + waves-before + rank
    int pre = 0;
    for (int cc = 0; cc < c; ++cc) pre += cntL[cc * NCLS + cls];
    int woff = 0;
    #pragma unroll
    for (int k = 0; k < 4; ++k) if (k < w) woff += wv[k * NCLS + cls];
    int dest = csL[cls] + pre + woff + rnk;
    clist[b * N_ + dest] = idx;
    cgS[b * N_ + dest] = cls;

    const float4* s4 = (const float4*)(pred + ((size_t)b * N_ + idx) * D_);
    float f[32];
    float ssq = 0.0f;
    #pragma unroll
    for (int k = 0; k < 8; ++k) {
        float4 q = s4[k];
        f[k * 4] = q.x; f[k * 4 + 1] = q.y; f[k * 4 + 2] = q.z; f[k * 4 + 3] = q.w;
        ssq += q.x * q.x + q.y * q.y + q.z * q.z + q.w * q.w;
    }
    float inv = 1.0f / fmaxf(sqrtf(ssq), 1e-12f);
    unsigned hw[16], lw[16];
    #pragma unroll
    for (int k = 0; k < 16; ++k) {
        float x0 = f[2 * k] * inv, x1 = f[2 * k + 1] * inv;
        unsigned short h0 = f2bf(x0), h1 = f2bf(x1);
        unsigned short l0 = f2bf(x0 - bf2f(h0)), l1 = f2bf(x1 - bf2f(h1));
        hw[k] = (unsigned)h0 | ((unsigned)h1 << 16);
        lw[k] = (unsigned)l0 | ((unsigned)l1 << 16);
    }
    uint4* dh = (uint4*)(hi_g + ((size_t)b * N_ + dest) * 32);
    uint4* dl = (uint4*)(lo_g + ((size_t)b * N_ + dest) * 32);
    #pragma unroll
    for (int k = 0; k < 4; ++k) {
        dh[k] = make_uint4(hw[4 * k], hw[4 * k + 1], hw[4 * k + 2], hw[4 * k + 3]);
        dl[k] = make_uint4(lw[4 * k], lw[4 * k + 1], lw[4 * k + 2], lw[4 * k + 3]);
    }
}

// ---------------- Kernel 2: MFMA pair pass + fused per-batch combine ----------------
// grid = (NPASS, B). Packed triangular (bi,bj) decode as in round 4 (verified).
// After its tile work, EVERY block (incl. early-exit) increments passDone[b];
// the 650th block for its batch runs the whole batch combine (deterministic:
// single block, fixed-order accumulate), publishes partS/partC[b], and the
// last batch-finisher does the final 4-slot reduce -> out.
// C/D layout: col = lane&15, row = (lane>>4)*4 + reg  [m89-verified].
__global__ __launch_bounds__(256) void k_pass(const unsigned short* __restrict__ hi_g,
                                              const unsigned short* __restrict__ lo_g,
                                              const int* __restrict__ cgS,
                                              const int* __restrict__ clist,
                                              const int* __restrict__ Marr,
                                              const int* __restrict__ csArr,
                                              const float* __restrict__ pos_rand,
                                              unsigned* __restrict__ bestArr,
                                              unsigned* __restrict__ passDone,
                                              unsigned* __restrict__ combDone,
                                              unsigned* __restrict__ partS,
                                              unsigned* __restrict__ partC,
                                              float* __restrict__ out) {
    int b = blockIdx.y;
    int M = Marr[b];
    // decode packed triangular index: bj s.t. bj(bj+1) <= f < (bj+1)(bj+2)
    int f = blockIdx.x;
    int bj = (int)((sqrtf(4.0f * (float)f + 1.0f) - 1.0f) * 0.5f);
    if ((bj + 1) * (bj + 2) <= f) ++bj;
    if (bj * (bj + 1) > f) --bj;
    int bi = f - bj * (bj + 1);
    int i0 = bi * TI;
    int j0 = bj * TJ;
    int t = threadIdx.x;
    int lane = t & 63, w = t >> 6;

    // LDS rows padded to 80 B (40 shorts): 16-lane frag reads = 2-way banks (free)
    __shared__ __align__(16) unsigned short sc_hi[TJ * 40];  // 20 KB
    __shared__ __align__(16) unsigned short sc_lo[TJ * 40];  // 20 KB
    __shared__ int sg[TJ];
    __shared__ float colb[4 * TJ];    // per-wave col-best (4 KB)

    bool activeBlk = (i0 < M) && (j0 < M);     // block-uniform
    if (activeBlk) {
        {
            int j = j0 + t;
            sg[t] = (j < M) ? cgS[b * N_ + j] : -1;
            #pragma unroll
            for (int k = 0; k < 4; ++k) colb[k * 256 + t] = -INFINITY;
        }
        {   // stage: thread -> (row = p*64 + t>>2, 16B seg = t&3); coalesced global reads
            int seg = t & 3, r0 = t >> 2;
            #pragma unroll
            for (int p = 0; p < 4; ++p) {
                int row = p * 64 + r0;
                int j = j0 + row;
                uint4 vh = make_uint4(0u, 0u, 0u, 0u), vl = make_uint4(0u, 0u, 0u, 0u);
                if (j < M) {
                    vh = *(const uint4*)(hi_g + ((size_t)b * N_ + j) * 32 + seg * 8);
                    vl = *(const uint4*)(lo_g + ((size_t)b * N_ + j) * 32 + seg * 8);
                }
                *(uint4*)(sc_hi + row * 40 + seg * 8) = vh;
                *(uint4*)(sc_lo + row * 40 + seg * 8) = vl;
            }
        }
        __syncthreads();

        int r = lane & 15, quad = lane >> 4;
        int ib = i0 + w * 32;            // this wave's 32 anchors (2 i-tiles)

        if (ib < M) {                    // inactive waves fall through to colb reduce
            bf16x8 a_hi[2], a_lo[2];
            int gt_i[2][4];
            #pragma unroll
            for (int it = 0; it < 2; ++it) {
                int i = ib + it * 16 + r;
                bf16x8 zh = {0, 0, 0, 0, 0, 0, 0, 0};
                a_hi[it] = zh; a_lo[it] = zh;
                if (i < M) {
                    a_hi[it] = *(const bf16x8*)(hi_g + ((size_t)b * N_ + i) * 32 + quad * 8);
                    a_lo[it] = *(const bf16x8*)(lo_g + ((size_t)b * N_ + i) * 32 + quad * 8);
                }
                #pragma unroll
                for (int r4 = 0; r4 < 4; ++r4) {
                    int ia = ib + it * 16 + quad * 4 + r4;
                    gt_i[it][r4] = (ia < M) ? cgS[b * N_ + ia] : -2;
                }
            }

            // wave's positive j-range (classes contiguous after sort)
            int ilast = min(ib + 31, M - 1);
            int cmin = cgS[b * N_ + ib];
            int cmax = cgS[b * N_ + ilast];
            int posLo = csArr[b * CSROW + cmin];
            int posHi = csArr[b * CSROW + cmax + 1];
            bool oneCls = (cmin == cmax);
            bool allValid = (ib + 31 < M);  // wave-uniform: all 32 anchors real

            float best[2][4];
            #pragma unroll
            for (int it = 0; it < 2; ++it)
                #pragma unroll
                for (int r4 = 0; r4 < 4; ++r4) best[it][r4] = -INFINITY;

            int jrows = min(TJ, M - j0);
            int ntile = (jrows + 15) >> 4;
            for (int jt = 0; jt < ntile; ++jt) {
                int jlo = j0 + jt * 16;
                int jvhi = min(jlo + 16, j0 + jrows);      // end of VALID j's in tile
                // all-positive tile: no negatives either side -> skip MFMAs
                if (oneCls && jlo >= posLo && jvhi <= posHi) continue;

                bf16x8 bh = *(const bf16x8*)(sc_hi + (jt * 16 + r) * 40 + quad * 8);
                bf16x8 bl = *(const bf16x8*)(sc_lo + (jt * 16 + r) * 40 + quad * 8);
                bool full = (jt * 16 + 16) <= jrows;
                float cb = -INFINITY;                      // this wave's col-best, col=lane&15

                if (full && (jlo + 16 <= posLo || jlo >= posHi)) {
                    if (allValid) {
                        // fastest path: all pairs valid negatives, no masks at all
                        #pragma unroll
                        for (int it = 0; it < 2; ++it) {
                            f32x4 acc = {0.f, 0.f, 0.f, 0.f};
                            acc = __builtin_amdgcn_mfma_f32_16x16x32_bf16(a_hi[it], bh, acc, 0, 0, 0);
                            acc = __builtin_amdgcn_mfma_f32_16x16x32_bf16(a_hi[it], bl, acc, 0, 0, 0);
                            acc = __builtin_amdgcn_mfma_f32_16x16x32_bf16(a_lo[it], bh, acc, 0, 0, 0);
                            #pragma unroll
                            for (int r4 = 0; r4 < 4; ++r4) {
                                float v = acc[r4];
                                best[it][r4] = fmaxf(best[it][r4], v);
                                cb = fmaxf(cb, v);
                            }
                        }
                    } else {
                        // fast path, tail i-block: mask invalid i rows on col side
                        #pragma unroll
                        for (int it = 0; it < 2; ++it) {
                            f32x4 acc = {0.f, 0.f, 0.f, 0.f};
                            acc = __builtin_amdgcn_mfma_f32_16x16x32_bf16(a_hi[it], bh, acc, 0, 0, 0);
                            acc = __builtin_amdgcn_mfma_f32_16x16x32_bf16(a_hi[it], bl, acc, 0, 0, 0);
                            acc = __builtin_amdgcn_mfma_f32_16x16x32_bf16(a_lo[it], bh, acc, 0, 0, 0);
                            #pragma unroll
                            for (int r4 = 0; r4 < 4; ++r4) {
                                float v = acc[r4];
                                best[it][r4] = fmaxf(best[it][r4], v);
                                cb = fmaxf(cb, (gt_i[it][r4] >= 0) ? v : -INFINITY);
                            }
                        }
                    }
                } else {
                    // straddle / tail path: per-element class compare
                    int gtj = sg[jt * 16 + r];
                    bool jv = (gtj >= 0);
                    #pragma unroll
                    for (int it = 0; it < 2; ++it) {
                        f32x4 acc = {0.f, 0.f, 0.f, 0.f};
                        acc = __builtin_amdgcn_mfma_f32_16x16x32_bf16(a_hi[it], bh, acc, 0, 0, 0);
                        acc = __builtin_amdgcn_mfma_f32_16x16x32_bf16(a_hi[it], bl, acc, 0, 0, 0);
                        acc = __builtin_amdgcn_mfma_f32_16x16x32_bf16(a_lo[it], bh, acc, 0, 0, 0);
                        #pragma unroll
                        for (int r4 = 0; r4 < 4; ++r4) {
                            bool same = (gtj == gt_i[it][r4]);
                            float sm = (same || !jv) ? -INFINITY : acc[r4];
                            best[it][r4] = fmaxf(best[it][r4], sm);
                            cb = fmaxf(cb, (gt_i[it][r4] >= 0) ? sm : -INFINITY);
                        }
                    }
                }

                // col-side reduce: lanes {c,c+16,c+32,c+48} all hold col c candidates
                cb = fmaxf(cb, __shfl_xor(cb, 16));
                cb = fmaxf(cb, __shfl_xor(cb, 32));
                if (lane < 16) colb[w * TJ + jt * 16 + lane] = cb;
            }

            // row-side epilogue
            #pragma unroll
            for (int it = 0; it < 2; ++it) {
                #pragma unroll
                for (int r4 = 0; r4 < 4; ++r4) {
                    float bb = best[it][r4];
                    #pragma unroll
                    for (int mk = 1; mk < 16; mk <<= 1)
                        bb = fmaxf(bb, __shfl_xor(bb, mk));
                    if (r == 0) {
                        int ia = ib + it * 16 + quad * 4 + r4;
                        if (ia < M && bb > -INFINITY)
                            atomicMax(&bestArr[b * N_ + ia], fmap(bb));
                    }
                }
            }
        }

        // col-side epilogue: combine 4 waves, one atomic per j per block
        __syncthreads();
        {
            float v = fmaxf(fmaxf(colb[t], colb[TJ + t]),
                            fmaxf(colb[2 * TJ + t], colb[3 * TJ + t]));
            int j = j0 + t;
            if (j < M && v > -INFINITY)
                atomicMax(&bestArr[b * N_ + j], fmap(v));
        }
    }

    // ---------------- fused per-batch combine (ticketed last block) ----------------
    __threadfence();                     // release our bestArr updates
    __shared__ int s_last;
    if (t == 0)
        s_last = (atomicAdd(&passDone[b], 1u) == (unsigned)(NPASS - 1)) ? 1 : 0;
    __syncthreads();
    if (!s_last) return;
    __threadfence();                     // acquire other blocks' updates

    // this block combines the whole batch, fixed order -> deterministic
    float csum = 0.0f;
    int ccnt = 0;
    for (int base = 0; base < M; base += 256) {   // M wave-uniform
        int i = base + t;
        if (i < M) {
            int cls = cgS[b * N_ + i];
            int s0 = csArr[b * CSROW + cls];
            int s1 = csArr[b * CSROW + cls + 1];
            int num_pos = s1 - s0 - 1;                    // class size minus self
            unsigned bu = atomicAdd(&bestArr[b * N_ + i], 0u);   // coherent read
            if (num_pos >= 1 && bu != NEG_INF_MAPPED) {
                float bestv = funmap(bu);
                int orig = clist[b * N_ + i];
                float u = pos_rand[b * N_ + orig];
                int pcx = (int)floorf(u * (float)num_pos);   // matches jnp f32 math
                int hi2 = num_pos - 1;
                pcx = pcx < 0 ? 0 : (pcx > hi2 ? hi2 : pcx);
                int ri = i - s0;                              // self's rank in class
                int posj = s0 + pcx + (pcx >= ri ? 1 : 0);    // k-th positive, orig order

                const uint4* xh4 = (const uint4*)(hi_g + ((size_t)b * N_ + i) * 32);
                const uint4* xl4 = (const uint4*)(lo_g + ((size_t)b * N_ + i) * 32);
                const uint4* yh4 = (const uint4*)(hi_g + ((size_t)b * N_ + posj) * 32);
                const uint4* yl4 = (const uint4*)(lo_g + ((size_t)b * N_ + posj) * 32);
                float dot = 0.0f;
                #pragma unroll
                for (int q = 0; q < 4; ++q) {
                    uint4 XH = xh4[q], XL = xl4[q], YH = yh4[q], YL = yl4[q];
                    dot += dpair(XH.x, XL.x, YH.x, YL.x);
                    dot += dpair(XH.y, XL.y, YH.y, YL.y);
                    dot += dpair(XH.z, XL.z, YH.z, YL.z);
                    dot += dpair(XH.w, XL.w, YH.w, YL.w);
                }
                float pos_d = sqrtf(fmaxf(2.f - 2.f * dot, 0.f) + 1e-12f);
                float neg_d = sqrtf(fmaxf(2.f - 2.f * bestv, 0.f) + 1e-12f);
                csum += fmaxf(pos_d - neg_d + MARGIN_, 0.0f);
                ccnt += 1;
            }
        }
    }

    // block reduce (fixed tree -> deterministic)
    #pragma unroll
    for (int off = 32; off > 0; off >>= 1) {
        csum += __shfl_down(csum, off);
        ccnt += __shfl_down(ccnt, off);
    }
    __shared__ float ssum[4];
    __shared__ int scnt[4];
    if (lane == 0) { ssum[w] = csum; scnt[w] = ccnt; }
    __syncthreads();

    if (t == 0) {
        float bs = ssum[0] + ssum[1] + ssum[2] + ssum[3];
        int bc = scnt[0] + scnt[1] + scnt[2] + scnt[3];
        atomicExch(&partS[b], __float_as_uint(bs));
        atomicExch(&partC[b], (unsigned)bc);
        __threadfence();
        if (atomicAdd(combDone, 1u) == (unsigned)(B_ - 1)) {
            float T = 0.0f; int C = 0;
            #pragma unroll
            for (int k = 0; k < B_; ++k) {               // fixed order, coherent reads
                T += __uint_as_float(atomicAdd(&partS[k], 0u));
                C += (int)atomicAdd(&partC[k], 0u);
            }
            out[0] = (C > 0) ? (T / (float)C) : 0.0f;
        }
    }
}

// ---------------- launch ----------------
extern "C" void kernel_launch(void* const* d_in, const int* in_sizes, int n_in,
                              void* d_out, int out_size, void* d_ws, size_t ws_size,
                              hipStream_t stream) {
    const float* pred     = (const float*)d_in[0];
    const float* pos_rand = (const float*)d_in[1];
    const int*   gt       = (const int*)d_in[2];
    const int*   fg       = (const int*)d_in[3];
    float* out = (float*)d_out;

    char* ws = (char*)d_ws;
    // layout (bytes):
    //   hi_g     : 0         .. 1,638,400   (B*N*32 bf16)
    //   lo_g     : 1,638,400 .. 3,276,800
    //   clist    : 3,276,800 .. 3,379,200   (B*N i32, class-sorted -> orig idx)
    //   cgS      : 3,379,200 .. 3,481,600   (B*N i32, sorted classes)
    //   Marr     : 3,481,600 .. 3,481,664
    //   csArr    : 3,481,664 .. 3,482,048   (B*CSROW i32 classStart)
    //   combDone : 3,482,048 (u32)
    //   passDone : 3,482,112 .. +16        (B u32)
    //   partS    : 3,482,176 .. +16        (B u32)
    //   partC    : 3,482,240 .. +16        (B u32)
    //   bestArr  : 3,483,136 .. 3,585,536  (B*N u32)
    unsigned short* hi_g     = (unsigned short*)(ws);
    unsigned short* lo_g     = (unsigned short*)(ws + 1638400);
    int*            clist    = (int*)(ws + 3276800);
    int*            cgS      = (int*)(ws + 3379200);
    int*            Marr     = (int*)(ws + 3481600);
    int*            csArr    = (int*)(ws + 3481664);
    unsigned*       combDone = (unsigned*)(ws + 3482048);
    unsigned*       passDone = (unsigned*)(ws + 3482112);
    unsigned*       partS    = (unsigned*)(ws + 3482176);
    unsigned*       partC    = (unsigned*)(ws + 3482240);
    unsigned*       bestArr  = (unsigned*)(ws + 3483136);

    dim3 gpr(NCC, B_);
    k_prep<<<gpr, 256, 0, stream>>>(pred, gt, fg, hi_g, lo_g, clist, cgS, Marr, csArr,
                                    bestArr, passDone, combDone);
    dim3 gp(NPASS, B_);
    k_pass<<<gp, 256, 0, stream>>>(hi_g, lo_g, cgS, clist, Marr, csArr, pos_rand,
                                   bestArr, passDone, combDone, partS, partC, out);
}

// Round 6
// 92.790 us; speedup vs baseline: 2.9560x; 2.9560x over previous
//
#include <hip/hip_runtime.h>
#include <math.h>

// Problem constants (fixed by the reference setup)
#define B_ 4
#define N_ 6400
#define D_ 32
#define TJ 256          // j-chunk staged in LDS (k_pass)
#define TI 128          // anchors per k_pass block (4 waves x 2 i-tiles x 16)
#define CHUNK 256       // compaction chunk
#define NCC 25          // N_/CHUNK
#define NCLS 20         // gt classes in [0,20)
#define CSROW 24        // padded row stride for per-batch classStart[21]
#define TOTB (NCC * B_) // k_combine blocks
// packed triangular k_pass grid: NI = N_/TI = 50, NJ = N_/TJ = 25.
// keep (bi,bj) iff bi*TI < (bj+1)*TJ  <=>  bi <= 2*bj+1  -> nbi(bj) = 2*bj+2
// cum(bj) = bj*(bj+1); total = 24*25 + 50 = 650
#define NPASS 650

typedef __attribute__((ext_vector_type(4))) float f32x4;
typedef __attribute__((ext_vector_type(8))) short bf16x8;

static constexpr float MARGIN_ = 0.3f;

// monotone float<->uint map so atomicMax(uint) == float max
__device__ __forceinline__ unsigned fmap(float f) {
    unsigned u = __float_as_uint(f);
    return (u & 0x80000000u) ? ~u : (u | 0x80000000u);
}
__device__ __forceinline__ float funmap(unsigned u) {
    return (u & 0x80000000u) ? __uint_as_float(u ^ 0x80000000u)
                             : __uint_as_float(~u);
}
#define NEG_INF_MAPPED 0x007FFFFFu   // fmap(-inf)

// round-to-nearest-even f32 -> bf16
__device__ __forceinline__ unsigned short f2bf(float f) {
    unsigned u = __float_as_uint(f);
    unsigned r = u + 0x7fffu + ((u >> 16) & 1u);
    return (unsigned short)(r >> 16);
}
__device__ __forceinline__ float bf2f(unsigned short h) {
    return __uint_as_float(((unsigned)h) << 16);
}
// unpack packed bf16 pair (elem even in low 16, odd in high 16)
__device__ __forceinline__ void bf2x(unsigned u, float& e0, float& e1) {
    e0 = __uint_as_float(u << 16);
    e1 = __uint_as_float(u & 0xffff0000u);
}
// fp32-reconstructed dot of one packed pair (hi+lo splits)
__device__ __forceinline__ float dpair(unsigned xh, unsigned xl, unsigned yh, unsigned yl) {
    float a0, a1, b0, b1, c0, c1, d0, d1;
    bf2x(xh, a0, a1); bf2x(xl, b0, b1);
    bf2x(yh, c0, c1); bf2x(yl, d0, d1);
    return fmaf(a0 + b0, c0 + d0, (a1 + b1) * (c1 + d1));
}

// ---------------- Kernel 1: prep = stable counting-sort by class ----------------
// grid (25, B) x 256. Each block counts ALL (chunk,class) pairs of its batch via
// LDS atomics (waves split chunks), derives classStart[] + per-chunk/per-wave
// offsets, then scatters its own chunk's fg elements CLASS-SORTED (stable by
// original index): writes normalized hi/lo bf16 rows, clist (orig idx), cgS
// (class). Block c==0 also writes Marr[b] and csArr[b][0..20]. Inits bestArr,
// zeroes the combine ticket.
__global__ __launch_bounds__(256) void k_prep(const float* __restrict__ pred,
                                              const int* __restrict__ gt,
                                              const int* __restrict__ fg,
                                              unsigned short* __restrict__ hi_g,
                                              unsigned short* __restrict__ lo_g,
                                              int* __restrict__ clist,
                                              int* __restrict__ cgS,
                                              int* __restrict__ Marr,
                                              int* __restrict__ csArr,
                                              unsigned* __restrict__ bestArr,
                                              unsigned* __restrict__ done) {
    int c = blockIdx.x, b = blockIdx.y;
    int t = threadIdx.x, lane = t & 63, w = t >> 6;
    int idx = c * CHUNK + t;

    bestArr[b * N_ + idx] = NEG_INF_MAPPED;
    if (c == 0 && b == 0 && t == 0) *done = 0u;

    __shared__ int cntL[NCC * NCLS];   // per-(chunk,class) counts, whole batch
    __shared__ int wv[4 * NCLS];       // own-chunk per-wave class counts
    __shared__ int totL[NCLS];
    __shared__ int csL[NCLS + 1];
    for (int k = t; k < NCC * NCLS; k += 256) cntL[k] = 0;
    __syncthreads();

    // phase 1: count all chunks; wave w takes chunks w, w+4, ...
    for (int cc = w; cc < NCC; cc += 4) {
        const int4 f4 = ((const int4*)(fg + (size_t)b * N_ + cc * CHUNK))[lane];
        const int4 g4 = ((const int4*)(gt + (size_t)b * N_ + cc * CHUNK))[lane];
        if (f4.x) atomicAdd(&cntL[cc * NCLS + g4.x], 1);
        if (f4.y) atomicAdd(&cntL[cc * NCLS + g4.y], 1);
        if (f4.z) atomicAdd(&cntL[cc * NCLS + g4.z], 1);
        if (f4.w) atomicAdd(&cntL[cc * NCLS + g4.w], 1);
    }

    // own element: stable rank within (own chunk, class)
    bool flag = fg[b * N_ + idx] != 0;
    int cls = flag ? gt[b * N_ + idx] : 0;
    int rnk = 0;
    unsigned long long below = (1ull << lane) - 1ull;
    for (int k = 0; k < NCLS; ++k) {
        unsigned long long m = __ballot(flag && (cls == k));
        if (flag && cls == k) rnk = __popcll(m & below);
        if (lane == 0) wv[w * NCLS + k] = __popcll(m);
    }
    __syncthreads();

    // phase 2: class totals and exclusive prefix (classStart)
    if (t < NCLS) {
        int s = 0;
        #pragma unroll
        for (int cc = 0; cc < NCC; ++cc) s += cntL[cc * NCLS + t];
        totL[t] = s;
    }
    __syncthreads();
    if (t <= NCLS) {
        int s = 0;
        for (int k = 0; k < t; ++k) s += totL[k];
        csL[t] = s;
    }
    __syncthreads();
    if (c == 0) {
        if (t == 0) Marr[b] = csL[NCLS];
        if (t <= NCLS) csArr[b * CSROW + t] = csL[t];
    }
    if (!flag) return;   // no further barriers below

    // phase 3: destination = classStart + chunks-before + waves-before + rank
    int pre = 0;
    for (int cc = 0; cc < c; ++cc) pre += cntL[cc * NCLS + cls];
    int woff = 0;
    #pragma unroll
    for (int k = 0; k < 4; ++k) if (k < w) woff += wv[k * NCLS + cls];
    int dest = csL[cls] + pre + woff + rnk;
    clist[b * N_ + dest] = idx;
    cgS[b * N_ + dest] = cls;

    const float4* s4 = (const float4*)(pred + ((size_t)b * N_ + idx) * D_);
    float f[32];
    float ssq = 0.0f;
    #pragma unroll
    for (int k = 0; k < 8; ++k) {
        float4 q = s4[k];
        f[k * 4] = q.x; f[k * 4 + 1] = q.y; f[k * 4 + 2] = q.z; f[k * 4 + 3] = q.w;
        ssq += q.x * q.x + q.y * q.y + q.z * q.z + q.w * q.w;
    }
    float inv = 1.0f / fmaxf(sqrtf(ssq), 1e-12f);
    unsigned hw[16], lw[16];
    #pragma unroll
    for (int k = 0; k < 16; ++k) {
        float x0 = f[2 * k] * inv, x1 = f[2 * k + 1] * inv;
        unsigned short h0 = f2bf(x0), h1 = f2bf(x1);
        unsigned short l0 = f2bf(x0 - bf2f(h0)), l1 = f2bf(x1 - bf2f(h1));
        hw[k] = (unsigned)h0 | ((unsigned)h1 << 16);
        lw[k] = (unsigned)l0 | ((unsigned)l1 << 16);
    }
    uint4* dh = (uint4*)(hi_g + ((size_t)b * N_ + dest) * 32);
    uint4* dl = (uint4*)(lo_g + ((size_t)b * N_ + dest) * 32);
    #pragma unroll
    for (int k = 0; k < 4; ++k) {
        dh[k] = make_uint4(hw[4 * k], hw[4 * k + 1], hw[4 * k + 2], hw[4 * k + 3]);
        dl[k] = make_uint4(lw[4 * k], lw[4 * k + 1], lw[4 * k + 2], lw[4 * k + 3]);
    }
}

// ---------------- Kernel 2: MFMA pair pass — TRIANGULAR, packed grid ----------------
// grid = (NPASS, B). Flat index f decodes to (bi,bj) covering ONLY blocks with
// bi*TI < (bj+1)*TJ (at/above the diagonal); below-diagonal pairs are covered
// by the transposed block's col-update (max is idempotent). Straddle blocks
// double-compute near the diagonal — harmless for max.
// Per j-tile (wave-uniform branch):
//   - tile all-positive & single class  -> skip entirely (no MFMA)
//   - full tile disjoint from positives -> no class compares; if additionally
//     all 32 anchors valid (allValid, wave-uniform) the col-best needs no
//     i-validity mask either (pure fmax both sides)
//   - straddling / tail tile            -> per-element class compare
// Col-side masks otherwise require i-validity (zero-padded rows give sim=0).
// C/D layout: col = lane&15, row = (lane>>4)*4 + reg  [m89-verified].
__global__ __launch_bounds__(256) void k_pass(const unsigned short* __restrict__ hi_g,
                                              const unsigned short* __restrict__ lo_g,
                                              const int* __restrict__ cgS,
                                              const int* __restrict__ Marr,
                                              const int* __restrict__ csArr,
                                              unsigned* __restrict__ bestArr) {
    int b = blockIdx.y;
    int M = Marr[b];
    // decode packed triangular index: bj s.t. bj(bj+1) <= f < (bj+1)(bj+2)
    int f = blockIdx.x;
    int bj = (int)((sqrtf(4.0f * (float)f + 1.0f) - 1.0f) * 0.5f);
    if ((bj + 1) * (bj + 2) <= f) ++bj;
    if (bj * (bj + 1) > f) --bj;
    int bi = f - bj * (bj + 1);
    int i0 = bi * TI;
    int j0 = bj * TJ;
    if (i0 >= M || j0 >= M) return;   // block-uniform exit

    // LDS rows padded to 80 B (40 shorts): 16-lane frag reads = 2-way banks (free)
    __shared__ __align__(16) unsigned short sc_hi[TJ * 40];  // 20 KB
    __shared__ __align__(16) unsigned short sc_lo[TJ * 40];  // 20 KB
    __shared__ int sg[TJ];
    __shared__ float colb[4 * TJ];    // per-wave col-best (4 KB)
    int t = threadIdx.x;

    {
        int j = j0 + t;
        sg[t] = (j < M) ? cgS[b * N_ + j] : -1;
        #pragma unroll
        for (int k = 0; k < 4; ++k) colb[k * 256 + t] = -INFINITY;
    }
    {   // stage: thread -> (row = p*64 + t>>2, 16B seg = t&3); coalesced global reads
        int seg = t & 3, r0 = t >> 2;
        #pragma unroll
        for (int p = 0; p < 4; ++p) {
            int row = p * 64 + r0;
            int j = j0 + row;
            uint4 vh = make_uint4(0u, 0u, 0u, 0u), vl = make_uint4(0u, 0u, 0u, 0u);
            if (j < M) {
                vh = *(const uint4*)(hi_g + ((size_t)b * N_ + j) * 32 + seg * 8);
                vl = *(const uint4*)(lo_g + ((size_t)b * N_ + j) * 32 + seg * 8);
            }
            *(uint4*)(sc_hi + row * 40 + seg * 8) = vh;
            *(uint4*)(sc_lo + row * 40 + seg * 8) = vl;
        }
    }
    __syncthreads();

    int lane = t & 63, w = t >> 6;
    int r = lane & 15, quad = lane >> 4;
    int ib = i0 + w * 32;            // this wave's 32 anchors (2 i-tiles)

    if (ib < M) {                    // inactive waves fall through to colb reduce
        bf16x8 a_hi[2], a_lo[2];
        int gt_i[2][4];
        #pragma unroll
        for (int it = 0; it < 2; ++it) {
            int i = ib + it * 16 + r;
            bf16x8 zh = {0, 0, 0, 0, 0, 0, 0, 0};
            a_hi[it] = zh; a_lo[it] = zh;
            if (i < M) {
                a_hi[it] = *(const bf16x8*)(hi_g + ((size_t)b * N_ + i) * 32 + quad * 8);
                a_lo[it] = *(const bf16x8*)(lo_g + ((size_t)b * N_ + i) * 32 + quad * 8);
            }
            #pragma unroll
            for (int r4 = 0; r4 < 4; ++r4) {
                int ia = ib + it * 16 + quad * 4 + r4;
                gt_i[it][r4] = (ia < M) ? cgS[b * N_ + ia] : -2;
            }
        }

        // wave's positive j-range (classes contiguous after sort)
        int ilast = min(ib + 31, M - 1);
        int cmin = cgS[b * N_ + ib];
        int cmax = cgS[b * N_ + ilast];
        int posLo = csArr[b * CSROW + cmin];
        int posHi = csArr[b * CSROW + cmax + 1];
        bool oneCls = (cmin == cmax);
        bool allValid = (ib + 31 < M);  // wave-uniform: all 32 anchors real

        float best[2][4];
        #pragma unroll
        for (int it = 0; it < 2; ++it)
            #pragma unroll
            for (int r4 = 0; r4 < 4; ++r4) best[it][r4] = -INFINITY;

        int jrows = min(TJ, M - j0);
        int ntile = (jrows + 15) >> 4;
        for (int jt = 0; jt < ntile; ++jt) {
            int jlo = j0 + jt * 16;
            int jvhi = min(jlo + 16, j0 + jrows);      // end of VALID j's in tile
            // all-positive tile: no negatives either side -> skip MFMAs
            if (oneCls && jlo >= posLo && jvhi <= posHi) continue;

            bf16x8 bh = *(const bf16x8*)(sc_hi + (jt * 16 + r) * 40 + quad * 8);
            bf16x8 bl = *(const bf16x8*)(sc_lo + (jt * 16 + r) * 40 + quad * 8);
            bool full = (jt * 16 + 16) <= jrows;
            float cb = -INFINITY;                      // this wave's col-best, col=lane&15

            if (full && (jlo + 16 <= posLo || jlo >= posHi)) {
                if (allValid) {
                    // fastest path: all pairs valid negatives, no masks at all
                    #pragma unroll
                    for (int it = 0; it < 2; ++it) {
                        f32x4 acc = {0.f, 0.f, 0.f, 0.f};
                        acc = __builtin_amdgcn_mfma_f32_16x16x32_bf16(a_hi[it], bh, acc, 0, 0, 0);
                        acc = __builtin_amdgcn_mfma_f32_16x16x32_bf16(a_hi[it], bl, acc, 0, 0, 0);
                        acc = __builtin_amdgcn_mfma_f32_16x16x32_bf16(a_lo[it], bh, acc, 0, 0, 0);
                        #pragma unroll
                        for (int r4 = 0; r4 < 4; ++r4) {
                            float v = acc[r4];
                            best[it][r4] = fmaxf(best[it][r4], v);
                            cb = fmaxf(cb, v);
                        }
                    }
                } else {
                    // fast path, tail i-block: mask invalid i rows on col side
                    #pragma unroll
                    for (int it = 0; it < 2; ++it) {
                        f32x4 acc = {0.f, 0.f, 0.f, 0.f};
                        acc = __builtin_amdgcn_mfma_f32_16x16x32_bf16(a_hi[it], bh, acc, 0, 0, 0);
                        acc = __builtin_amdgcn_mfma_f32_16x16x32_bf16(a_hi[it], bl, acc, 0, 0, 0);
                        acc = __builtin_amdgcn_mfma_f32_16x16x32_bf16(a_lo[it], bh, acc, 0, 0, 0);
                        #pragma unroll
                        for (int r4 = 0; r4 < 4; ++r4) {
                            float v = acc[r4];
                            best[it][r4] = fmaxf(best[it][r4], v);
                            cb = fmaxf(cb, (gt_i[it][r4] >= 0) ? v : -INFINITY);
                        }
                    }
                }
            } else {
                // straddle / tail path: per-element class compare
                int gtj = sg[jt * 16 + r];
                bool jv = (gtj >= 0);
                #pragma unroll
                for (int it = 0; it < 2; ++it) {
                    f32x4 acc = {0.f, 0.f, 0.f, 0.f};
                    acc = __builtin_amdgcn_mfma_f32_16x16x32_bf16(a_hi[it], bh, acc, 0, 0, 0);
                    acc = __builtin_amdgcn_mfma_f32_16x16x32_bf16(a_hi[it], bl, acc, 0, 0, 0);
                    acc = __builtin_amdgcn_mfma_f32_16x16x32_bf16(a_lo[it], bh, acc, 0, 0, 0);
                    #pragma unroll
                    for (int r4 = 0; r4 < 4; ++r4) {
                        bool same = (gtj == gt_i[it][r4]);
                        float sm = (same || !jv) ? -INFINITY : acc[r4];
                        best[it][r4] = fmaxf(best[it][r4], sm);
                        cb = fmaxf(cb, (gt_i[it][r4] >= 0) ? sm : -INFINITY);
                    }
                }
            }

            // col-side reduce: lanes {c,c+16,c+32,c+48} all hold col c candidates
            cb = fmaxf(cb, __shfl_xor(cb, 16));
            cb = fmaxf(cb, __shfl_xor(cb, 32));
            if (lane < 16) colb[w * TJ + jt * 16 + lane] = cb;
        }

        // row-side epilogue
        #pragma unroll
        for (int it = 0; it < 2; ++it) {
            #pragma unroll
            for (int r4 = 0; r4 < 4; ++r4) {
                float bb = best[it][r4];
                #pragma unroll
                for (int mk = 1; mk < 16; mk <<= 1)
                    bb = fmaxf(bb, __shfl_xor(bb, mk));
                if (r == 0) {
                    int ia = ib + it * 16 + quad * 4 + r4;
                    if (ia < M && bb > -INFINITY)
                        atomicMax(&bestArr[b * N_ + ia], fmap(bb));
                }
            }
        }
    }

    // col-side epilogue: combine 4 waves, one atomic per j per block
    __syncthreads();
    {
        float v = fmaxf(fmaxf(colb[t], colb[TJ + t]),
                        fmaxf(colb[2 * TJ + t], colb[3 * TJ + t]));
        int j = j0 + t;
        if (j < M && v > -INFINITY)
            atomicMax(&bestArr[b * N_ + j], fmap(v));
    }
}

// ---------------- Kernel 3: combine + fused final (deterministic last-block) ----------------
// grid (25, B) x 256, thread-per-anchor. Class-sorted layout makes num_pos and
// the random-positive index O(1). Block partials -> atomicExch slots; last
// block (device-scope ticket) reduces the 100 slots in a FIXED order -> out.
__global__ __launch_bounds__(256) void k_combine(const unsigned short* __restrict__ hi_g,
                                                 const unsigned short* __restrict__ lo_g,
                                                 const int* __restrict__ cgS,
                                                 const int* __restrict__ clist,
                                                 const int* __restrict__ Marr,
                                                 const int* __restrict__ csArr,
                                                 const float* __restrict__ pos_rand,
                                                 const unsigned* __restrict__ bestArr,
                                                 unsigned* __restrict__ partS,
                                                 unsigned* __restrict__ partC,
                                                 unsigned* __restrict__ done,
                                                 float* __restrict__ out) {
    int b = blockIdx.y;
    int M = Marr[b];
    int t = threadIdx.x, lane = t & 63, w = t >> 6;
    int i = blockIdx.x * 256 + t;

    float contrib = 0.0f;
    int vflag = 0;
    if (i < M) {
        int cls = cgS[b * N_ + i];
        int s0 = csArr[b * CSROW + cls];
        int s1 = csArr[b * CSROW + cls + 1];
        int num_pos = s1 - s0 - 1;                    // class size minus self
        unsigned bu = bestArr[b * N_ + i];
        if (num_pos >= 1 && bu != NEG_INF_MAPPED) {   // bu!=NEG_INF <=> a negative exists
            float best = funmap(bu);
            int orig = clist[b * N_ + i];
            float u = pos_rand[b * N_ + orig];
            int pcx = (int)floorf(u * (float)num_pos);   // matches jnp f32 math
            int hi2 = num_pos - 1;
            pcx = pcx < 0 ? 0 : (pcx > hi2 ? hi2 : pcx);
            int ri = i - s0;                              // self's rank in class
            int posj = s0 + pcx + (pcx >= ri ? 1 : 0);    // k-th positive, orig order

            const uint4* xh4 = (const uint4*)(hi_g + ((size_t)b * N_ + i) * 32);
            const uint4* xl4 = (const uint4*)(lo_g + ((size_t)b * N_ + i) * 32);
            const uint4* yh4 = (const uint4*)(hi_g + ((size_t)b * N_ + posj) * 32);
            const uint4* yl4 = (const uint4*)(lo_g + ((size_t)b * N_ + posj) * 32);
            float dot = 0.0f;
            #pragma unroll
            for (int q = 0; q < 4; ++q) {
                uint4 XH = xh4[q], XL = xl4[q], YH = yh4[q], YL = yl4[q];
                dot += dpair(XH.x, XL.x, YH.x, YL.x);
                dot += dpair(XH.y, XL.y, YH.y, YL.y);
                dot += dpair(XH.z, XL.z, YH.z, YL.z);
                dot += dpair(XH.w, XL.w, YH.w, YL.w);
            }
            float pos_d = sqrtf(fmaxf(2.f - 2.f * dot, 0.f) + 1e-12f);
            float neg_d = sqrtf(fmaxf(2.f - 2.f * best, 0.f) + 1e-12f);
            contrib = fmaxf(pos_d - neg_d + MARGIN_, 0.0f);
            vflag = 1;
        }
    }

    // block reduce (fixed tree -> deterministic)
    #pragma unroll
    for (int off = 32; off > 0; off >>= 1) {
        contrib += __shfl_down(contrib, off);
        vflag += __shfl_down(vflag, off);
    }
    __shared__ float ssum[4];
    __shared__ int scnt[4];
    if (lane == 0) { ssum[w] = contrib; scnt[w] = vflag; }
    __syncthreads();

    if (w == 0) {
        int bid = b * NCC + blockIdx.x;
        int last = 0;
        if (lane == 0) {
            float bs = ssum[0] + ssum[1] + ssum[2] + ssum[3];
            int bc = scnt[0] + scnt[1] + scnt[2] + scnt[3];
            atomicExch(&partS[bid], __float_as_uint(bs));
            atomicExch(&partC[bid], (unsigned)bc);
            __threadfence();
            last = (atomicAdd(done, 1u) == (unsigned)(TOTB - 1)) ? 1 : 0;
        }
        last = __shfl(last, 0);
        if (last) {
            float T = 0.0f; int C = 0;
            for (int k = lane; k < TOTB; k += 64) {        // coherent atomic reads
                T += __uint_as_float(atomicAdd(&partS[k], 0u));
                C += (int)atomicAdd(&partC[k], 0u);
            }
            #pragma unroll
            for (int off = 32; off > 0; off >>= 1) {       // fixed tree, deterministic
                T += __shfl_down(T, off);
                C += __shfl_down(C, off);
            }
            if (lane == 0) out[0] = (C > 0) ? (T / (float)C) : 0.0f;
        }
    }
}

// ---------------- launch ----------------
extern "C" void kernel_launch(void* const* d_in, const int* in_sizes, int n_in,
                              void* d_out, int out_size, void* d_ws, size_t ws_size,
                              hipStream_t stream) {
    const float* pred     = (const float*)d_in[0];
    const float* pos_rand = (const float*)d_in[1];
    const int*   gt       = (const int*)d_in[2];
    const int*   fg       = (const int*)d_in[3];
    float* out = (float*)d_out;

    char* ws = (char*)d_ws;
    // layout (bytes):
    //   hi_g    : 0         .. 1,638,400   (B*N*32 bf16)
    //   lo_g    : 1,638,400 .. 3,276,800
    //   clist   : 3,276,800 .. 3,379,200   (B*N i32, class-sorted -> orig idx)
    //   cgS     : 3,379,200 .. 3,481,600   (B*N i32, sorted classes)
    //   Marr    : 3,481,600 .. 3,481,664
    //   csArr   : 3,481,664 .. 3,482,048   (B*CSROW i32 classStart)
    //   done    : 3,482,048 .. 3,482,112
    //   partS   : 3,482,112 .. 3,482,624   (TOTB u32)
    //   partC   : 3,482,624 .. 3,483,136
    //   bestArr : 3,483,136 .. 3,585,536   (B*N u32)
    unsigned short* hi_g    = (unsigned short*)(ws);
    unsigned short* lo_g    = (unsigned short*)(ws + 1638400);
    int*            clist   = (int*)(ws + 3276800);
    int*            cgS     = (int*)(ws + 3379200);
    int*            Marr    = (int*)(ws + 3481600);
    int*            csArr   = (int*)(ws + 3481664);
    unsigned*       done    = (unsigned*)(ws + 3482048);
    unsigned*       partS   = (unsigned*)(ws + 3482112);
    unsigned*       partC   = (unsigned*)(ws + 3482624);
    unsigned*       bestArr = (unsigned*)(ws + 3483136);

    dim3 gpr(NCC, B_);
    k_prep<<<gpr, 256, 0, stream>>>(pred, gt, fg, hi_g, lo_g, clist, cgS, Marr, csArr, bestArr, done);
    dim3 gp(NPASS, B_);
    k_pass<<<gp, 256, 0, stream>>>(hi_g, lo_g, cgS, Marr, csArr, bestArr);
    dim3 gc(NCC, B_);
    k_combine<<<gc, 256, 0, stream>>>(hi_g, lo_g, cgS, clist, Marr, csArr, pos_rand, bestArr, partS, partC, done, out);
}